// Round 1
// baseline (117.898 us; speedup 1.0000x reference)
//
#include <hip/hip_runtime.h>
#include <hip/hip_bf16.h>

// PairwiseScore: B=2, N=256, E=512, H=150 (padded to 160)
// out[b,i,j] = (m[b,i] + m[b,j] + MLP3(g_i, g_j)) / 3
//
// Fold: hij + hj = sum_e (g_i[e]*W1c[e,h] + W1b[e,h]) * g_j[e]
// R4 structure (one block per (b,i), 512 thr):
//  - mega-tile shrunk 8kt->4kt (stage 80KB->40KB) => LDS ~44KB => 2 blocks/CU
//    co-resident (was 1). Barrier stalls of one block now overlap with the
//    other block's MFMA/build phases.
//  - W2TF staging dropped: GEMM2 A-frags read direct from L2 (50KB, hot,
//    1KB/instr coalesced). Entire tail after GEMM1 is barrier-free.
//  - prep_pack W1 pack split 3-ways (8 loads/thread, 120 blocks) to cut the
//    latency-bound serialization of the old 24-load/thread version.

typedef __attribute__((ext_vector_type(4))) float f32x4;
typedef __attribute__((ext_vector_type(4))) unsigned int u32x4;
typedef __attribute__((ext_vector_type(2))) unsigned int u32x2;
typedef __attribute__((ext_vector_type(8))) short short8;

#define NB 2
#define NN 256
#define NE 512
#define NH 150
#define HP 160      // padded H
#define NKT 16      // NE/32 k-tiles for GEMM1
#define NKM 4       // k-tiles per mega
#define NMEGA 4     // NKT/NKM
#define NHT 10      // HP/16 h-tiles
#define NS 5        // HP/32 k-steps for GEMM2

// ---------- helpers ----------
__device__ __forceinline__ unsigned pk_bf16(float a, float b) {
  unsigned ua = __builtin_bit_cast(unsigned, a);
  unsigned ub = __builtin_bit_cast(unsigned, b);
  ua += 0x7fffu + ((ua >> 16) & 1u);
  ub += 0x7fffu + ((ub >> 16) & 1u);
  return (ua >> 16) | (ub & 0xffff0000u);
}
__device__ __forceinline__ float bf_lo(unsigned u) { return __builtin_bit_cast(float, u << 16); }
__device__ __forceinline__ float bf_hi(unsigned u) { return __builtin_bit_cast(float, u & 0xffff0000u); }

// ---------- prep: grid 389 x 256 ----------
//  bid [0,256)    : g (f32) -> g_bf16
//  bid [256,376)  : W1a/W1b/W1c -> WaF/WbF/WcF frag-major [(kt*10+ht)*64+lane]*8
//                   (one matrix per 40-block slice: 8 loads/thread)
//  bid [376,389)  : W2^T -> W2TF frag-major [(s*10+ht)*64+lane]*8
__global__ __launch_bounds__(256) void prep_pack(
    const float* __restrict__ g, const float* __restrict__ W1,
    const float* __restrict__ W2,
    unsigned short* __restrict__ g_bf16, unsigned short* __restrict__ WaF,
    unsigned short* __restrict__ WbF, unsigned short* __restrict__ WcF,
    unsigned short* __restrict__ W2TF)
{
  int bid = blockIdx.x, tid = threadIdx.x;
  if (bid < 256) {
    int t = bid * 256 + tid;                 // 65536 float4s = 262144 floats
    f32x4 v = ((const f32x4*)g)[t];
    u32x2 o; o[0] = pk_bf16(v[0], v[1]); o[1] = pk_bf16(v[2], v[3]);
    ((u32x2*)g_bf16)[t] = o;
  } else if (bid < 376) {
    int bb = bid - 256;
    int mat = bb / 40;                       // 0=a, 1=b, 2=c
    int row = (bb - mat * 40) * 256 + tid;   // 0..10239 = 16kt*10ht*64lane
    int kt = row / 640; int rem = row - kt * 640;
    int l = rem & 63; int chh = rem >> 6;
    int e = kt * 32 + (l >> 4) * 8;
    int h = chh * 16 + (l & 15);
    const float* __restrict__ Wm = W1 + (size_t)(mat * NE) * NH;
    u32x4 o;
#pragma unroll
    for (int q = 0; q < 4; ++q) {
      int e0 = e + 2 * q, e1 = e0 + 1;
      float v0 = 0.f, v1 = 0.f;
      if (h < NH) {
        v0 = Wm[(size_t)e0 * NH + h];
        v1 = Wm[(size_t)e1 * NH + h];
      }
      o[q] = pk_bf16(v0, v1);
    }
    unsigned short* dst = (mat == 0) ? WaF : (mat == 1) ? WbF : WcF;
    ((u32x4*)dst)[row] = o;
  } else {
    int row = (bid - 376) * 256 + tid;       // < 3200 = 5s*10ht*64lane
    if (row < 3200) {
      int s = row / 640; int rem = row - s * 640;
      int l = rem & 63; int chh = rem >> 6;
      int k = s * 32 + (l >> 4) * 8;
      int hp = chh * 16 + (l & 15);
      u32x4 o;
#pragma unroll
      for (int q = 0; q < 4; ++q) {
        int k0 = k + 2 * q, k1 = k0 + 1;
        float v0 = (k0 < NH && hp < NH) ? W2[(size_t)k0 * NH + hp] : 0.f;
        float v1 = (k1 < NH && hp < NH) ? W2[(size_t)k1 * NH + hp] : 0.f;
        o[q] = pk_bf16(v0, v1);
      }
      ((u32x4*)W2TF)[row] = o;
    }
  }
}

// ---------- main fused kernel: 512 threads, one block per (b,i) ----------
__global__ __launch_bounds__(512, 4) void pair_main(
    const float* __restrict__ mention, const float* __restrict__ b1,
    const float* __restrict__ b2, const float* __restrict__ W3,
    const float* __restrict__ b3,
    const unsigned short* __restrict__ g_bf16,
    const unsigned short* __restrict__ WaF,
    const unsigned short* __restrict__ WbF, const unsigned short* __restrict__ WcF,
    const unsigned short* __restrict__ W2TF,
    float* __restrict__ out)
{
  __shared__ unsigned int stage[NKM * NHT * 64 * 4];  // 40 KB: one 4-kt A~ mega-tile
  __shared__ unsigned int gi_lds[NE / 2];             // g_i as bf16 (1 KB)
  __shared__ alignas(16) float bias1[HP];             // b1 + hi  (hi added via mini-MFMA)
  __shared__ alignas(16) float bias2[HP];
  __shared__ alignas(16) float w3s[HP];

  const int tid = threadIdx.x;
  const int bi = blockIdx.x;
  const int b = bi >> 8, i = bi & 255;
  const int lane = tid & 63, wave = tid >> 6;       // 8 waves
  const int c16 = lane & 15, quad = lane >> 4;

  // ---- phase 0: per-block constants into LDS ----
  {
    const u32x4* grow = (const u32x4*)(g_bf16 + (size_t)(b * NN + i) * NE);
    if (tid < 64) ((u32x4*)gi_lds)[tid] = grow[tid];
    if (tid < HP) {
      int h = tid;
      bias1[h] = (h < NH) ? b1[h] : 0.f;
      bias2[h] = (h < NH) ? b2[h] : 0.f;
      w3s[h]   = (h < NH) ? W3[h] : 0.f;
    }
  }
  __syncthreads();   // barrier A

  // ---- builder for one 4-kt mega-tile: exactly 5 rows/thread (2560 rows) ----
  auto build_mega = [&](int mega) {
#pragma unroll
    for (int r = 0; r < 5; ++r) {
      int v = tid + r * 512;                 // 0..2559
      int ktl = v / 640; int rem = v - ktl * 640;
      int l = rem & 63;
      int ktg = mega * NKM + ktl;
      int gidx = ktg * 640 + (rem >> 6) * 64 + l;
      u32x4 wb = ((const u32x4*)WbF)[gidx];
      u32x4 wc = ((const u32x4*)WcF)[gidx];
      u32x4 gi = ((const u32x4*)gi_lds)[ktg * 4 + (l >> 4)];
      u32x4 o;
#pragma unroll
      for (int q = 0; q < 4; ++q) {
        float lo = bf_lo(gi[q]) * bf_lo(wc[q]) + bf_lo(wb[q]);
        float hi = bf_hi(gi[q]) * bf_hi(wc[q]) + bf_hi(wb[q]);
        o[q] = pk_bf16(lo, hi);
      }
      ((u32x4*)stage)[v] = o;
    }
  };

  // ---- mega 0 build; waves 0-4 also compute hi via mini-MFMA (broadcast B) ----
  build_mega(0);
  if (wave < 5) {
    f32x4 ah0 = {}, ah1 = {};
#pragma unroll
    for (int kt = 0; kt < NKT; ++kt) {
      short8 bbc = __builtin_bit_cast(short8, ((const u32x4*)gi_lds)[kt * 4 + quad]);
      short8 a0 = __builtin_bit_cast(short8,
          ((const u32x4*)WaF)[(kt * NHT + 2 * wave) * 64 + lane]);
      short8 a1 = __builtin_bit_cast(short8,
          ((const u32x4*)WaF)[(kt * NHT + 2 * wave + 1) * 64 + lane]);
      ah0 = __builtin_amdgcn_mfma_f32_16x16x32_bf16(a0, bbc, ah0, 0, 0, 0);
      ah1 = __builtin_amdgcn_mfma_f32_16x16x32_bf16(a1, bbc, ah1, 0, 0, 0);
    }
    if (c16 == 0) {
#pragma unroll
      for (int r = 0; r < 4; ++r) {
        bias1[(2 * wave) * 16 + quad * 4 + r]     += ah0[r];
        bias1[(2 * wave + 1) * 16 + quad * 4 + r] += ah1[r];
      }
    }
  }
  __syncthreads();   // barrier B: mega-0 A~ + bias1 ready

  // ---- phase 1: D1[h][j] = A~ * g_j, 4 mega-phases ----
  f32x4 acc1[NHT][2] = {};
  const u32x4* gB = (const u32x4*)g_bf16;
  const int jbase = wave * 32 + c16;
  const size_t gidx0 = (size_t)(b * NN + jbase) * 64 + quad;  // u32x4 units

#pragma unroll 1
  for (int mega = 0; mega < NMEGA; ++mega) {
#pragma unroll
    for (int ktl = 0; ktl < NKM; ++ktl) {
      int ktg = mega * NKM + ktl;
      short8 bf0 = __builtin_bit_cast(short8, gB[gidx0 + (size_t)ktg * 4]);
      short8 bf1 = __builtin_bit_cast(short8, gB[gidx0 + 16 * 64 + (size_t)ktg * 4]);
      const u32x4* As = (const u32x4*)stage + ktl * (NHT * 64);
#pragma unroll
      for (int ht = 0; ht < NHT; ++ht) {
        short8 af = __builtin_bit_cast(short8, As[ht * 64 + lane]);
        acc1[ht][0] = __builtin_amdgcn_mfma_f32_16x16x32_bf16(af, bf0, acc1[ht][0], 0, 0, 0);
        acc1[ht][1] = __builtin_amdgcn_mfma_f32_16x16x32_bf16(af, bf1, acc1[ht][1], 0, 0, 0);
      }
    }
    if (mega < NMEGA - 1) {
      __syncthreads();   // mega reads done
      build_mega(mega + 1);
      __syncthreads();   // next A~ ready
    }
  }
  // no barrier: tail (epilogues + GEMM2) touches no shared LDS buffers

  // ---- epilogue 1: h1 = relu(D1 + hi + b1) -> bf16 in registers ----
  // lane holds h = 16*ht + 4*quad + r, j = wave*32 + jt*16 + c16
  unsigned Hlo[NHT][2], Hhi[NHT][2];
#pragma unroll
  for (int ht = 0; ht < NHT; ++ht) {
    f32x4 bv = *(const f32x4*)(bias1 + ht * 16 + quad * 4);
#pragma unroll
    for (int jt = 0; jt < 2; ++jt) {
      f32x4 v = acc1[ht][jt];
      float r0 = fmaxf(v[0] + bv[0], 0.f);
      float r1 = fmaxf(v[1] + bv[1], 0.f);
      float r2 = fmaxf(v[2] + bv[2], 0.f);
      float r3 = fmaxf(v[3] + bv[3], 0.f);
      Hlo[ht][jt] = pk_bf16(r0, r1);
      Hhi[ht][jt] = pk_bf16(r2, r3);
    }
  }

  // ---- phase 2: D2[h'][j] = W2^T * h1 ; h1 C-layout -> B-frag via shfl ----
  // A-frags read direct from L2-resident W2TF (50KB, shared by all blocks).
  f32x4 acc2[NHT][2] = {};
  const int lA = ((lane >> 4) & 1) * 32 + c16;  // source lane for d0..3
  const int lB = lA + 16;                        // source lane for d4..7
  const bool selHi = ((lane >> 5) & 1) != 0;     // quads 2,3 take t=2s+1
  const u32x4* A2g = (const u32x4*)W2TF;

#pragma unroll
  for (int s = 0; s < NS; ++s) {
    short8 b2f[2];
#pragma unroll
    for (int jt = 0; jt < 2; ++jt) {
      unsigned a0 = (unsigned)__shfl((int)Hlo[2 * s][jt], lA);
      unsigned a1 = (unsigned)__shfl((int)Hhi[2 * s][jt], lA);
      unsigned a2 = (unsigned)__shfl((int)Hlo[2 * s][jt], lB);
      unsigned a3 = (unsigned)__shfl((int)Hhi[2 * s][jt], lB);
      unsigned d0 = (unsigned)__shfl((int)Hlo[2 * s + 1][jt], lA);
      unsigned d1 = (unsigned)__shfl((int)Hhi[2 * s + 1][jt], lA);
      unsigned d2 = (unsigned)__shfl((int)Hlo[2 * s + 1][jt], lB);
      unsigned d3 = (unsigned)__shfl((int)Hhi[2 * s + 1][jt], lB);
      u32x4 fr;
      fr[0] = selHi ? d0 : a0;
      fr[1] = selHi ? d1 : a1;
      fr[2] = selHi ? d2 : a2;
      fr[3] = selHi ? d3 : a3;
      b2f[jt] = __builtin_bit_cast(short8, fr);
    }
#pragma unroll
    for (int ht = 0; ht < NHT; ++ht) {
      short8 af = __builtin_bit_cast(short8, A2g[(s * NHT + ht) * 64 + lane]);
      acc2[ht][0] = __builtin_amdgcn_mfma_f32_16x16x32_bf16(af, b2f[0], acc2[ht][0], 0, 0, 0);
      acc2[ht][1] = __builtin_amdgcn_mfma_f32_16x16x32_bf16(af, b2f[1], acc2[ht][1], 0, 0, 0);
    }
  }

  // ---- epilogue 2 + GEMM3: score[j] = sum_h' relu(D2 + b2)*W3 ----
  float part0 = 0.f, part1 = 0.f;
#pragma unroll
  for (int ht = 0; ht < NHT; ++ht) {
    f32x4 bv = *(const f32x4*)(bias2 + ht * 16 + quad * 4);
    f32x4 wv = *(const f32x4*)(w3s + ht * 16 + quad * 4);
    f32x4 v0 = acc2[ht][0], v1 = acc2[ht][1];
#pragma unroll
    for (int r = 0; r < 4; ++r) {
      part0 += fmaxf(v0[r] + bv[r], 0.f) * wv[r];
      part1 += fmaxf(v1[r] + bv[r], 0.f) * wv[r];
    }
  }
  part0 += __shfl_xor(part0, 16); part0 += __shfl_xor(part0, 32);
  part1 += __shfl_xor(part1, 16); part1 += __shfl_xor(part1, 32);

  const float mi = mention[b * NN + i];
  const float b3v = b3[0];
  float sc = (quad == 0) ? part0 : part1;
  if (quad < 2) {
    int j = wave * 32 + quad * 16 + c16;
    float mj = mention[b * NN + j];
    out[((size_t)(b * NN + i)) * NN + j] = (mi + mj + sc + b3v) * (1.f / 3.f);
  }
}

// ---------- launch ----------
extern "C" void kernel_launch(void* const* d_in, const int* in_sizes, int n_in,
                              void* d_out, int out_size, void* d_ws, size_t ws_size,
                              hipStream_t stream) {
  const float* g  = (const float*)d_in[0];
  const float* m  = (const float*)d_in[1];
  const float* W1 = (const float*)d_in[2];
  const float* b1 = (const float*)d_in[3];
  const float* W2 = (const float*)d_in[4];
  const float* b2 = (const float*)d_in[5];
  const float* W3 = (const float*)d_in[6];
  const float* b3 = (const float*)d_in[7];
  float* out = (float*)d_out;

  char* ws = (char*)d_ws;
  unsigned short* g_bf16 = (unsigned short*)(ws);              // 524288 B
  unsigned short* WaF    = (unsigned short*)(ws + 524288);     // 163840 B
  unsigned short* WbF    = (unsigned short*)(ws + 688128);     // 163840 B
  unsigned short* WcF    = (unsigned short*)(ws + 851968);     // 163840 B
  unsigned short* W2TF   = (unsigned short*)(ws + 1015808);    //  51200 B (total ~1.02 MB)

  prep_pack<<<389, 256, 0, stream>>>(g, W1, W2, g_bf16, WaF, WbF, WcF, W2TF);
  pair_main<<<512, 512, 0, stream>>>(m, b1, b2, W3, b3, g_bf16, WaF, WbF, WcF, W2TF, out);
}